// Round 4
// baseline (522.315 us; speedup 1.0000x reference)
//
#include <hip/hip_runtime.h>
#include <hip/hip_bf16.h>

#define N_ROWS 8192
#define F_DIM  256
#define KSPLIT 4

typedef __bf16 bf16x8_t __attribute__((ext_vector_type(8)));
typedef float  f32x4_t  __attribute__((ext_vector_type(4)));

static __device__ __forceinline__ unsigned short f2bf(float x) {
    union { __hip_bfloat16 h; unsigned short u; } c;
    c.h = __float2bfloat16(x);   // RNE
    return c.u;
}
static __device__ __forceinline__ unsigned pk2(float lo, float hi) {
    return (unsigned)f2bf(lo) | ((unsigned)f2bf(hi) << 16);
}

// async global->LDS, 16B per lane; LDS dst = wave-uniform base + lane*16
static __device__ __forceinline__ void gload16(const unsigned short* g, unsigned short* s) {
    __builtin_amdgcn_global_load_lds((const __attribute__((address_space(1))) void*)g,
                                     (__attribute__((address_space(3))) void*)s, 16, 0, 0);
}

// ---------------------------------------------------------------------------
// K0: W [256][256] fp32 -> bf16, swizzled Ws[kb][n][kc]  (kb=k>>5, kc=k&31)
// B-fragment (lane: n=l&15, k=q*8+j) is one contiguous 16B load.
// ---------------------------------------------------------------------------
__global__ __launch_bounds__(256) void wconv_kernel(const float* __restrict__ W,
                                                    unsigned short* __restrict__ Ws) {
    const int kb = blockIdx.x;            // 8 blocks of 32 k-rows
    const int t  = threadIdx.x;
    __shared__ float wt[32][257];
    const int r = t >> 3, g = t & 7;
    const float* src = W + (kb * 32 + r) * F_DIM + g * 32;
#pragma unroll
    for (int i = 0; i < 8; ++i) {
        float4 v = *(const float4*)(src + i * 4);
        wt[r][g * 32 + i * 4 + 0] = v.x;
        wt[r][g * 32 + i * 4 + 1] = v.y;
        wt[r][g * 32 + i * 4 + 2] = v.z;
        wt[r][g * 32 + i * 4 + 3] = v.w;
    }
    __syncthreads();
    unsigned o[16];
#pragma unroll
    for (int k = 0; k < 32; k += 2) o[k >> 1] = pk2(wt[k][t], wt[k + 1][t]);
    uint4* dst = (uint4*)(Ws + kb * 8192 + t * 32);
#pragma unroll
    for (int i = 0; i < 4; ++i) dst[i] = make_uint4(o[4*i], o[4*i+1], o[4*i+2], o[4*i+3]);
}

// ---------------------------------------------------------------------------
// K1: per 32-row band: rowsum(A) -> d; Abf = bf16(A) row-major;
// Xrm = bf16(d * H) row-major.  268 MB read, 142 MB write -> HBM-bound.
// ---------------------------------------------------------------------------
__global__ __launch_bounds__(1024) void sumconv_kernel(const float* __restrict__ A,
                                                       const float* __restrict__ H,
                                                       float* __restrict__ dvec,
                                                       unsigned short* __restrict__ Abf,
                                                       unsigned short* __restrict__ Xrm) {
    const int kb = blockIdx.x;            // 256 blocks, 32 rows each
    const int t  = threadIdx.x;
    __shared__ float psum[32][33];
    __shared__ float dl[32];

    const int r = t >> 5, g = t & 31;     // 32 threads per row
    const int row = kb * 32 + r;
    const float* arow = A + (size_t)row * N_ROWS;
    unsigned short* aout = Abf + (size_t)row * N_ROWS;
    float s0 = 0.f, s1 = 0.f, s2 = 0.f, s3 = 0.f;
#pragma unroll 8
    for (int i = 0; i < 64; ++i) {
        const int e = (i * 32 + g) * 4;
        float4 v = *(const float4*)(arow + e);
        s0 += v.x; s1 += v.y; s2 += v.z; s3 += v.w;
        uint2 p = make_uint2(pk2(v.x, v.y), pk2(v.z, v.w));
        *(uint2*)(aout + e) = p;
    }
    psum[r][g] = (s0 + s1) + (s2 + s3);
    __syncthreads();
    if (t < 32) {
        float s = 0.f;
#pragma unroll
        for (int i = 0; i < 32; ++i) s += psum[t][i];
        float d = 1.0f / sqrtf(s);
        dl[t] = d;
        dvec[kb * 32 + t] = d;
    }
    __syncthreads();
    {   // Xrm = d * H, row-major bf16 (A-operand friendly)
        const int hr = t >> 5, hg = t & 31;
        const int hrow = kb * 32 + hr;
        const float* hsrc = H + (size_t)hrow * F_DIM + hg * 8;
        float4 v0 = ((const float4*)hsrc)[0];
        float4 v1 = ((const float4*)hsrc)[1];
        const float d = dl[hr];
        uint4 o = make_uint4(pk2(v0.x * d, v0.y * d), pk2(v0.z * d, v0.w * d),
                             pk2(v1.x * d, v1.y * d), pk2(v1.z * d, v1.w * d));
        *(uint4*)(Xrm + (size_t)hrow * F_DIM + hg * 8) = o;
    }
}

// ---------------------------------------------------------------------------
// K2: X2 = Xrm @ Ws  (8192x256 @ 256x256), output bf16 swizzled
// X2s[k>>5][n][k&31] (k = H-row = biggemm contraction dim, n = out col).
// 128 blocks x 256 thr, 4 waves; wave = 16 rows x 256 cols; no LDS/barrier.
// ---------------------------------------------------------------------------
__global__ __launch_bounds__(256) void x2gemm_kernel(const unsigned short* __restrict__ Xrm,
                                                     const unsigned short* __restrict__ Ws,
                                                     unsigned short* __restrict__ X2s) {
    const int t = threadIdx.x;
    const int w = t >> 6, l = t & 63;
    const int m16 = l & 15, q = l >> 4, q8 = q * 8;
    const int rbase = blockIdx.x * 64 + w * 16;

    f32x4_t acc[16] = {};
    const unsigned short* ap = Xrm + (size_t)(rbase + m16) * F_DIM + q8;
#pragma unroll
    for (int kb = 0; kb < 8; ++kb) {        // BK = 32
        bf16x8_t af = __builtin_bit_cast(bf16x8_t, *(const uint4*)(ap + kb * 32));
        const unsigned short* bp = Ws + kb * 8192 + m16 * 32 + q8;
#pragma unroll
        for (int nt = 0; nt < 16; ++nt) {
            bf16x8_t bf = __builtin_bit_cast(bf16x8_t, *(const uint4*)(bp + nt * 512));
            acc[nt] = __builtin_amdgcn_mfma_f32_16x16x32_bf16(af, bf, acc[nt], 0, 0, 0);
        }
    }
    // epilogue: rows kr = rbase + q*4 + {0..3} (contiguous within 32-block),
    // col c = nt*16 + m16.  Write 4 bf16 = uint2 per ntile.
    const int kr0 = rbase + q * 4;
    unsigned short* op = X2s + (kr0 >> 5) * 8192 + m16 * 32 + (kr0 & 31);
#pragma unroll
    for (int nt = 0; nt < 16; ++nt) {
        uint2 o = make_uint2(pk2(acc[nt][0], acc[nt][1]), pk2(acc[nt][2], acc[nt][3]));
        *(uint2*)(op + nt * 512) = o;
    }
}

// ---------------------------------------------------------------------------
// K3: Yp[ks] = Abf[64-row band, k-slice] @ X2s.  BM=64, BN=256 (full width ->
// A staged ONCE), BK=64.  256 thr, 4 waves (wave w: cols w*64, tile 64x64).
// A via LDS dbuf (gload16, 8KB/buf); B direct global->VGPR, prefetch 1 iter.
// Grid 512 = 128 mi x 4 ks -> 2 blocks/CU; ks = bid&3 pins XCD<->k-slice.
// ---------------------------------------------------------------------------
__global__ __launch_bounds__(256, 2) void biggemm_kernel(const unsigned short* __restrict__ Abf,
                                                         const unsigned short* __restrict__ X2s,
                                                         float* __restrict__ Ypart) {
    const int t = threadIdx.x;
    const int w = t >> 6, l = t & 63;
    const int m16 = l & 15, q = l >> 4, q8 = q * 8;
    const int bid = blockIdx.x;
    const int ks = bid & 3, mi = bid >> 2;        // mi 0..127
    const int kbase = ks * 2048;

    __shared__ __align__(16) unsigned short lds[2][4096];   // 2 x 8 KB (A only)

    // A staging: 2 gload16/thread; idx = w*2+j in 0..7 -> ft = idx>>1, s = idx&1
    const unsigned short* ag[2];
    int aslot[2];
#pragma unroll
    for (int j = 0; j < 2; ++j) {
        const int idx = w * 2 + j, ft = idx >> 1, s = idx & 1;
        ag[j] = Abf + (size_t)(mi * 64 + ft * 16 + m16) * N_ROWS + kbase + s * 32 + q8;
        aslot[j] = idx * 512;
    }
    // B: wave w covers cols w*64 .. w*64+63 (4 ntiles)
    const unsigned short* bptr = X2s + (kbase >> 5) * 8192 + (w * 64 + m16) * 32 + q8;

    f32x4_t acc[4][4] = {};

    // prologue
#pragma unroll
    for (int j = 0; j < 2; ++j) gload16(ag[j], &lds[0][aslot[j]]);
    uint4 bcur[2][4];
#pragma unroll
    for (int s = 0; s < 2; ++s)
#pragma unroll
        for (int nt = 0; nt < 4; ++nt)
            bcur[s][nt] = *(const uint4*)(bptr + s * 8192 + nt * 512);

    const int KITERS = 2048 / 64;                 // 32
    for (int i = 0; i < KITERS; ++i) {
        __syncthreads();                          // drains prev-iter A (age = 1 iter)
        const int cb = i & 1;
        uint4 bnxt[2][4];
        if (i + 1 < KITERS) {
#pragma unroll
            for (int j = 0; j < 2; ++j)
                gload16(ag[j] + (i + 1) * 64, &lds[cb ^ 1][aslot[j]]);
            const unsigned short* bp = bptr + (i + 1) * 16384;
#pragma unroll
            for (int s = 0; s < 2; ++s)
#pragma unroll
                for (int nt = 0; nt < 4; ++nt)
                    bnxt[s][nt] = *(const uint4*)(bp + s * 8192 + nt * 512);
        }
#pragma unroll
        for (int s = 0; s < 2; ++s) {
            bf16x8_t af[4];
#pragma unroll
            for (int mt = 0; mt < 4; ++mt)
                af[mt] = *(const bf16x8_t*)&lds[cb][(mt * 2 + s) * 512 + l * 8];
#pragma unroll
            for (int mt = 0; mt < 4; ++mt)
#pragma unroll
                for (int nt = 0; nt < 4; ++nt)
                    acc[mt][nt] = __builtin_amdgcn_mfma_f32_16x16x32_bf16(
                        af[mt], __builtin_bit_cast(bf16x8_t, bcur[s][nt]), acc[mt][nt], 0, 0, 0);
        }
#pragma unroll
        for (int s = 0; s < 2; ++s)
#pragma unroll
            for (int nt = 0; nt < 4; ++nt)
                bcur[s][nt] = bnxt[s][nt];
    }

    float* Y = Ypart + (size_t)ks * (N_ROWS * F_DIM);
#pragma unroll
    for (int mt = 0; mt < 4; ++mt) {
#pragma unroll
        for (int r = 0; r < 4; ++r) {
            const int row = mi * 64 + mt * 16 + q * 4 + r;
#pragma unroll
            for (int nt = 0; nt < 4; ++nt) {
                const int col = w * 64 + nt * 16 + m16;
                Y[(size_t)row * F_DIM + col] = acc[mt][nt][r];
            }
        }
    }
}

// ---------------------------------------------------------------------------
// K4: out = relu(d * (Yp0+Yp1+Yp2+Yp3)), elementwise fp32, float4.
// ---------------------------------------------------------------------------
__global__ __launch_bounds__(256) void reduce_kernel(const float* __restrict__ Ypart,
                                                     const float* __restrict__ dvec,
                                                     float* __restrict__ out) {
    const int idx = blockIdx.x * 256 + threadIdx.x;       // float4 index
    const int row = idx >> 6;                             // 64 float4 per row
    const float d = dvec[row];
    const size_t YS = (size_t)N_ROWS * F_DIM / 4;
    const float4* yp = (const float4*)Ypart;
    float4 a = yp[idx];
    float4 b = yp[idx + YS];
    float4 c = yp[idx + 2 * YS];
    float4 e = yp[idx + 3 * YS];
    float4 o;
    o.x = fmaxf(d * (a.x + b.x + c.x + e.x), 0.f);
    o.y = fmaxf(d * (a.y + b.y + c.y + e.y), 0.f);
    o.z = fmaxf(d * (a.z + b.z + c.z + e.z), 0.f);
    o.w = fmaxf(d * (a.w + b.w + c.w + e.w), 0.f);
    ((float4*)out)[idx] = o;
}

// ---------------------------------------------------------------------------
extern "C" void kernel_launch(void* const* d_in, const int* in_sizes, int n_in,
                              void* d_out, int out_size, void* d_ws, size_t ws_size,
                              hipStream_t stream) {
    (void)in_sizes; (void)n_in; (void)out_size; (void)ws_size;
    const float* H = (const float*)d_in[0];
    const float* A = (const float*)d_in[1];
    const float* W = (const float*)d_in[2];
    float* out = (float*)d_out;

    char* ws = (char*)d_ws;
    size_t off = 0;
    float*          dvec = (float*)(ws + off);           off += (32 << 10);
    unsigned short* Xrm  = (unsigned short*)(ws + off);  off += (4 << 20);
    unsigned short* Wsz  = (unsigned short*)(ws + off);  off += (128 << 10);
    unsigned short* X2s  = (unsigned short*)(ws + off);  off += (4 << 20);
    float*          Yp   = (float*)(ws + off);           off += (size_t)KSPLIT * N_ROWS * F_DIM * 4;
    unsigned short* Abf  = (unsigned short*)(ws + off);  off += (size_t)N_ROWS * N_ROWS * 2;

    wconv_kernel  <<<dim3(8),    dim3(256),  0, stream>>>(W, Wsz);
    sumconv_kernel<<<dim3(256),  dim3(1024), 0, stream>>>(A, H, dvec, Abf, Xrm);
    x2gemm_kernel <<<dim3(128),  dim3(256),  0, stream>>>(Xrm, Wsz, X2s);
    biggemm_kernel<<<dim3(512),  dim3(256),  0, stream>>>(Abf, X2s, Yp);
    reduce_kernel <<<dim3(2048), dim3(256),  0, stream>>>(Yp, dvec, out);
}

// Round 5
// 516.799 us; speedup vs baseline: 1.0107x; 1.0107x over previous
//
#include <hip/hip_runtime.h>
#include <hip/hip_bf16.h>

#define N_ROWS 8192
#define F_DIM  256
#define KSPLIT 4

typedef __bf16 bf16x8_t __attribute__((ext_vector_type(8)));
typedef float  f32x4_t  __attribute__((ext_vector_type(4)));

static __device__ __forceinline__ unsigned short f2bf(float x) {
    union { __hip_bfloat16 h; unsigned short u; } c;
    c.h = __float2bfloat16(x);   // RNE
    return c.u;
}
static __device__ __forceinline__ unsigned pk2(float lo, float hi) {
    return (unsigned)f2bf(lo) | ((unsigned)f2bf(hi) << 16);
}

// ---------------------------------------------------------------------------
// K0: W [256][256] fp32 -> bf16, swizzled Ws[kb][n][kc]  (kb=k>>5, kc=k&31)
// B-fragment (lane: n=l&15, k=q*8+j) is one contiguous 16B load.
// ---------------------------------------------------------------------------
__global__ __launch_bounds__(256) void wconv_kernel(const float* __restrict__ W,
                                                    unsigned short* __restrict__ Ws) {
    const int kb = blockIdx.x;            // 8 blocks of 32 k-rows
    const int t  = threadIdx.x;
    __shared__ float wt[32][257];
    const int r = t >> 3, g = t & 7;
    const float* src = W + (kb * 32 + r) * F_DIM + g * 32;
#pragma unroll
    for (int i = 0; i < 8; ++i) {
        float4 v = *(const float4*)(src + i * 4);
        wt[r][g * 32 + i * 4 + 0] = v.x;
        wt[r][g * 32 + i * 4 + 1] = v.y;
        wt[r][g * 32 + i * 4 + 2] = v.z;
        wt[r][g * 32 + i * 4 + 3] = v.w;
    }
    __syncthreads();
    unsigned o[16];
#pragma unroll
    for (int k = 0; k < 32; k += 2) o[k >> 1] = pk2(wt[k][t], wt[k + 1][t]);
    uint4* dst = (uint4*)(Ws + kb * 8192 + t * 32);
#pragma unroll
    for (int i = 0; i < 4; ++i) dst[i] = make_uint4(o[4*i], o[4*i+1], o[4*i+2], o[4*i+3]);
}

// ---------------------------------------------------------------------------
// K1: per 32-row band: rowsum(A) -> dvec;  Abf = bf16(A) row-major.
// 268 MB read + 134 MB write, pure streaming.
// ---------------------------------------------------------------------------
__global__ __launch_bounds__(1024) void sumconv_kernel(const float* __restrict__ A,
                                                       float* __restrict__ dvec,
                                                       unsigned short* __restrict__ Abf) {
    const int kb = blockIdx.x;            // 256 blocks, 32 rows each
    const int t  = threadIdx.x;
    __shared__ float psum[32][33];

    const int r = t >> 5, g = t & 31;     // 32 threads per row
    const int row = kb * 32 + r;
    const float* arow = A + (size_t)row * N_ROWS;
    unsigned short* aout = Abf + (size_t)row * N_ROWS;
    float s0 = 0.f, s1 = 0.f, s2 = 0.f, s3 = 0.f;
#pragma unroll 8
    for (int i = 0; i < 64; ++i) {
        const int e = (i * 32 + g) * 4;
        float4 v = *(const float4*)(arow + e);
        s0 += v.x; s1 += v.y; s2 += v.z; s3 += v.w;
        uint2 p = make_uint2(pk2(v.x, v.y), pk2(v.z, v.w));
        *(uint2*)(aout + e) = p;
    }
    psum[r][g] = (s0 + s1) + (s2 + s3);
    __syncthreads();
    if (t < 32) {
        float s = 0.f;
#pragma unroll
        for (int i = 0; i < 32; ++i) s += psum[t][i];
        dvec[kb * 32 + t] = 1.0f / sqrtf(s);
    }
}

// ---------------------------------------------------------------------------
// K2: X2 = (d∘H) @ Ws  (8192x256 @ 256x256), H fp32 scaled by d at load,
// output bf16 swizzled X2s[k>>5][n][k&31] (k = H-row index = biggemm
// contraction dim, n = out col).  128 blocks x 256 thr; no LDS/barrier.
// ---------------------------------------------------------------------------
__global__ __launch_bounds__(256) void x2gemm_kernel(const float* __restrict__ H,
                                                     const float* __restrict__ dvec,
                                                     const unsigned short* __restrict__ Ws,
                                                     unsigned short* __restrict__ X2s) {
    const int t = threadIdx.x;
    const int w = t >> 6, l = t & 63;
    const int m16 = l & 15, q = l >> 4, q8 = q * 8;
    const int rbase = blockIdx.x * 64 + w * 16;

    f32x4_t acc[16] = {};
    const int arow = rbase + m16;
    const float d = dvec[arow];
    const float* ap = H + (size_t)arow * F_DIM + q8;
#pragma unroll
    for (int kb = 0; kb < 8; ++kb) {        // BK = 32
        float4 u0 = *(const float4*)(ap + kb * 32);
        float4 u1 = *(const float4*)(ap + kb * 32 + 4);
        uint4 aw = make_uint4(pk2(u0.x * d, u0.y * d), pk2(u0.z * d, u0.w * d),
                              pk2(u1.x * d, u1.y * d), pk2(u1.z * d, u1.w * d));
        bf16x8_t af = __builtin_bit_cast(bf16x8_t, aw);
        const unsigned short* bp = Ws + kb * 8192 + m16 * 32 + q8;
#pragma unroll
        for (int nt = 0; nt < 16; ++nt) {
            bf16x8_t bf = __builtin_bit_cast(bf16x8_t, *(const uint4*)(bp + nt * 512));
            acc[nt] = __builtin_amdgcn_mfma_f32_16x16x32_bf16(af, bf, acc[nt], 0, 0, 0);
        }
    }
    // rows kr = rbase + q*4 + {0..3}; col c = nt*16 + m16; 4 bf16 = uint2.
    const int kr0 = rbase + q * 4;
    unsigned short* op = X2s + (kr0 >> 5) * 8192 + m16 * 32 + (kr0 & 31);
#pragma unroll
    for (int nt = 0; nt < 16; ++nt) {
        uint2 o = make_uint2(pk2(acc[nt][0], acc[nt][1]), pk2(acc[nt][2], acc[nt][3]));
        *(uint2*)(op + nt * 512) = o;
    }
}

// ---------------------------------------------------------------------------
// K3: Yp[ks] = Abf[64-row band, k-slice] @ X2s.  BARRIER-FREE: no LDS.
// Block = 4 waves; wave w computes rows mi*64..+63 x cols w*64..+63.
// A-frags: direct 16B global loads (all 4 waves load the same addresses ->
// L1 replication; unique HBM/L3 traffic = 134 MB once).
// B-frags: direct 16B loads from L2-resident X2s (4 MB).
// Depth-2 register pipeline (two frag buffers, loads 2 steps ahead), fine-
// grained vmcnt scheduling by the compiler -- no vmcnt(0) barrier drain.
// Grid 512 = 128 mi x 4 ks -> 2 blocks/CU, 8 waves/CU.
// ---------------------------------------------------------------------------
struct Frag { uint4 a[4]; uint4 b[4]; };

static __device__ __forceinline__ void load_step(Frag& f,
                                                 const unsigned short* aB,
                                                 const unsigned short* bB, int s) {
#pragma unroll
    for (int mt = 0; mt < 4; ++mt)
        f.a[mt] = *(const uint4*)(aB + (size_t)mt * 16 * N_ROWS + s * 32);
#pragma unroll
    for (int nt = 0; nt < 4; ++nt)
        f.b[nt] = *(const uint4*)(bB + nt * 512 + (size_t)s * 8192);
}

static __device__ __forceinline__ void compute_step(f32x4_t acc[4][4], const Frag& f) {
#pragma unroll
    for (int mt = 0; mt < 4; ++mt)
#pragma unroll
        for (int nt = 0; nt < 4; ++nt)
            acc[mt][nt] = __builtin_amdgcn_mfma_f32_16x16x32_bf16(
                __builtin_bit_cast(bf16x8_t, f.a[mt]),
                __builtin_bit_cast(bf16x8_t, f.b[nt]), acc[mt][nt], 0, 0, 0);
}

__global__ __launch_bounds__(256, 2) void biggemm_kernel(const unsigned short* __restrict__ Abf,
                                                         const unsigned short* __restrict__ X2s,
                                                         float* __restrict__ Ypart) {
    const int t = threadIdx.x;
    const int w = t >> 6, l = t & 63;
    const int m16 = l & 15, q = l >> 4, q8 = q * 8;
    const int bid = blockIdx.x;
    const int ks = bid & 3, mi = bid >> 2;        // mi 0..127
    const int kbase = ks * 2048;

    const unsigned short* aB = Abf + (size_t)(mi * 64 + m16) * N_ROWS + kbase + q8;
    const unsigned short* bB = X2s + (kbase >> 5) * 8192 + (w * 64 + m16) * 32 + q8;

    f32x4_t acc[4][4] = {};

    Frag f0, f1;
    load_step(f0, aB, bB, 0);
    load_step(f1, aB, bB, 1);

    const int STEPS = 2048 / 32;                  // 64
    for (int s = 0; s < STEPS; s += 2) {
        compute_step(acc, f0);
        if (s + 2 < STEPS) load_step(f0, aB, bB, s + 2);
        compute_step(acc, f1);
        if (s + 3 < STEPS) load_step(f1, aB, bB, s + 3);
    }

    float* Y = Ypart + (size_t)ks * (N_ROWS * F_DIM);
#pragma unroll
    for (int mt = 0; mt < 4; ++mt) {
#pragma unroll
        for (int r = 0; r < 4; ++r) {
            const int row = mi * 64 + mt * 16 + q * 4 + r;
#pragma unroll
            for (int nt = 0; nt < 4; ++nt) {
                const int col = w * 64 + nt * 16 + m16;
                Y[(size_t)row * F_DIM + col] = acc[mt][nt][r];
            }
        }
    }
}

// ---------------------------------------------------------------------------
// K4: out = relu(d * (Yp0+Yp1+Yp2+Yp3)), elementwise fp32, float4.
// ---------------------------------------------------------------------------
__global__ __launch_bounds__(256) void reduce_kernel(const float* __restrict__ Ypart,
                                                     const float* __restrict__ dvec,
                                                     float* __restrict__ out) {
    const int idx = blockIdx.x * 256 + threadIdx.x;       // float4 index
    const int row = idx >> 6;                             // 64 float4 per row
    const float d = dvec[row];
    const size_t YS = (size_t)N_ROWS * F_DIM / 4;
    const float4* yp = (const float4*)Ypart;
    float4 a = yp[idx];
    float4 b = yp[idx + YS];
    float4 c = yp[idx + 2 * YS];
    float4 e = yp[idx + 3 * YS];
    float4 o;
    o.x = fmaxf(d * (a.x + b.x + c.x + e.x), 0.f);
    o.y = fmaxf(d * (a.y + b.y + c.y + e.y), 0.f);
    o.z = fmaxf(d * (a.z + b.z + c.z + e.z), 0.f);
    o.w = fmaxf(d * (a.w + b.w + c.w + e.w), 0.f);
    ((float4*)out)[idx] = o;
}

// ---------------------------------------------------------------------------
extern "C" void kernel_launch(void* const* d_in, const int* in_sizes, int n_in,
                              void* d_out, int out_size, void* d_ws, size_t ws_size,
                              hipStream_t stream) {
    (void)in_sizes; (void)n_in; (void)out_size; (void)ws_size;
    const float* H = (const float*)d_in[0];
    const float* A = (const float*)d_in[1];
    const float* W = (const float*)d_in[2];
    float* out = (float*)d_out;

    char* ws = (char*)d_ws;
    size_t off = 0;
    float*          dvec = (float*)(ws + off);           off += (32 << 10);
    unsigned short* Wsz  = (unsigned short*)(ws + off);  off += (128 << 10);
    unsigned short* X2s  = (unsigned short*)(ws + off);  off += (4 << 20);
    float*          Yp   = (float*)(ws + off);           off += (size_t)KSPLIT * N_ROWS * F_DIM * 4;
    unsigned short* Abf  = (unsigned short*)(ws + off);  off += (size_t)N_ROWS * N_ROWS * 2;

    wconv_kernel  <<<dim3(8),    dim3(256),  0, stream>>>(W, Wsz);
    sumconv_kernel<<<dim3(256),  dim3(1024), 0, stream>>>(A, dvec, Abf);
    x2gemm_kernel <<<dim3(128),  dim3(256),  0, stream>>>(H, dvec, Wsz, X2s);
    biggemm_kernel<<<dim3(512),  dim3(256),  0, stream>>>(Abf, X2s, Yp);
    reduce_kernel <<<dim3(2048), dim3(256),  0, stream>>>(Yp, dvec, out);
}